// Round 19
// baseline (263.947 us; speedup 1.0000x reference)
//
#include <hip/hip_runtime.h>
#include <math.h>

#define NN 8192
#define NE 65536
#define NG 16
#define NEL 10
#define CC 64
#define NLM 16
#define MAXST 32
#define CAP 20
#define NWIN 512
#define PI_F 3.14159265358979f

__device__ __forceinline__ int lm_l(int lm) {
    return (lm == 0) ? 0 : (lm < 4) ? 1 : (lm < 9) ? 2 : 3;
}

// stage cnt packed records (24 floats each) + sender ids into per-wave LDS, coalesced
__device__ __forceinline__ void stage_pack(
    const float* __restrict__ PK, const int* __restrict__ SSND,
    int beg, int cnt, int c, float* sPK, int* sS)
{
    int tot = cnt * 24;
    for (int i = c; i < tot; i += 64) sPK[i] = PK[(size_t)beg*24 + i];
    if (c < cnt) sS[c] = SSND[beg + c];
    __builtin_amdgcn_wave_barrier();
}

// ---------- fused front: [0,256) geom->slots | [256,768) h0/elem/hist | [768,778) vb1 ----------
__global__ __launch_bounds__(256) void k_front(
    const float* __restrict__ pos, const float* __restrict__ shifts,
    const int* __restrict__ snd, const int* __restrict__ rcv,
    int* __restrict__ cur,
    float* __restrict__ PK, int* __restrict__ SSND, float* __restrict__ UL,
    const float* __restrict__ attrs, const float* __restrict__ Wemb,
    float* __restrict__ h0, int* __restrict__ elem, int* __restrict__ ecnt,
    const float* __restrict__ Wprod1, const float* __restrict__ wread,
    float* __restrict__ vb1)
{
    __shared__ int hcnt[NEL];
    int bx = blockIdx.x;
    if (bx < 256) {
        int e = bx * 256 + threadIdx.x;
        int s = snd[e], r = rcv[e];
        float vx = pos[r*3+0] - pos[s*3+0] + shifts[e*3+0];
        float vy = pos[r*3+1] - pos[s*3+1] + shifts[e*3+1];
        float vz = pos[r*3+2] - pos[s*3+2] + shifts[e*3+2];
        float len = sqrtf(vx*vx + vy*vy + vz*vz + 1e-9f);
        if (len >= 5.0f) return;   // cut==0 AND d(cut*bessel)/dr==0: exactly zero fwd+bwd
        int idx = atomicAdd(&cur[r], 1);
        if (idx >= CAP) return;    // guard (never expected: P(live deg>20) ~ 1e-11)
        int p = r*CAP + idx;
        float x = vx/len, y = vy/len, z = vz/len;
        float x2 = x*x, y2 = y*y, z2 = z*z;
        float4* d = (float4*)(PK + (size_t)p*24);
        d[0] = make_float4(0.28209479177387814f,
                           0.4886025119029199f*y,
                           0.4886025119029199f*z,
                           0.4886025119029199f*x);
        d[1] = make_float4(1.0925484305920792f*x*y,
                           1.0925484305920792f*y*z,
                           0.31539156525252005f*(3.f*z2 - 1.f),
                           1.0925484305920792f*x*z);
        d[2] = make_float4(0.5462742152960396f*(x2 - y2),
                           0.5900435899266435f*y*(3.f*x2 - y2),
                           2.890611442640554f*x*y*z,
                           0.4570457994644658f*y*(5.f*z2 - 1.f));
        d[3] = make_float4(0.3731763325901154f*z*(5.f*z2 - 3.f),
                           0.4570457994644658f*x*(5.f*z2 - 1.f),
                           1.445305721320277f*z*(x2 - y2),
                           0.5900435899266435f*x*(x2 - 3.f*y2));
        float ur = len * 0.2f;
        float u2 = ur*ur, u4 = u2*u2, u5 = u4*ur, u6 = u5*ur, u7 = u6*ur;
        float cut = 1.f - 21.f*u5 + 35.f*u6 - 15.f*u7;
        const float s2f = 0.632455532033676f;
        float th = (PI_F/5.f) * len;
        float s1, c1; sincosf(th, &s1, &c1);
        float sn_ = s1, cs = c1;
        float coef = s2f * cut / len;
        float rv[8];
#pragma unroll
        for (int nb = 0; nb < 8; nb++) {
            rv[nb] = coef * sn_;
            float ns = sn_*c1 + cs*s1;
            float nc = cs*c1 - sn_*s1;
            sn_ = ns; cs = nc;
        }
        d[4] = make_float4(rv[0], rv[1], rv[2], rv[3]);
        d[5] = make_float4(rv[4], rv[5], rv[6], rv[7]);
        SSND[p] = s;
        ((float4*)UL)[p] = make_float4(x, y, z, len);
    } else if (bx < 768) {
        int t = threadIdx.x, c = t & 63, w = t >> 6;
        if (t < NEL) hcnt[t] = 0;
        __syncthreads();
        for (int g = 0; g < 4; g++) {
            int n = (bx - 256)*16 + w*4 + g;
            float hv = 0.f;
            for (int el = 0; el < NEL; el++) hv += attrs[n*NEL+el] * Wemb[el*CC+c];
            h0[(size_t)n*CC+c] = hv;
            if (c == 0) {
                int el = 0;
                for (int k = 0; k < NEL; k++)
                    if (attrs[n*NEL+k] > 0.5f) el = k;
                elem[n] = el;
                atomicAdd(&hcnt[el], 1);
            }
        }
        __syncthreads();
        if (threadIdx.x < NEL) {
            int v = hcnt[threadIdx.x];
            if (v) atomicAdd(&ecnt[threadIdx.x], v);
        }
    } else {
        int el = bx - 768, f = threadIdx.x;
        float s = 0.f;
        for (int c = 0; c < CC; c++) s += wread[c] * Wprod1[(size_t)el*256*CC + f*CC + c];
        vb1[el*256+f] = s;
    }
}

// ---------- tiny element-offset scan ----------
__global__ void k_escan(const int* __restrict__ ecnt, int* __restrict__ eoff)
{
    if (threadIdx.x == 0) {
        int r = 0;
        for (int el = 0; el < NEL; el++) { eoff[el] = r; r += ecnt[el]; }
        eoff[NEL] = r;
    }
}

// ---------- nbe scatter + GH1/out zeroing ----------
__global__ __launch_bounds__(256) void k_nbe(
    const int* __restrict__ elem, const int* __restrict__ eoff,
    int* __restrict__ ecur, int* __restrict__ nbe,
    float* __restrict__ gh1, float* __restrict__ out)
{
    int n = blockIdx.x * blockDim.x + threadIdx.x;
    float4* g4 = (float4*)gh1;
#pragma unroll
    for (int k = 0; k < 16; k++) g4[(size_t)n*16 + k] = make_float4(0.f, 0.f, 0.f, 0.f);
    for (int i = n; i < NG + NN*3; i += NN) out[i] = 0.f;
    int el = elem[n];
    int p = eoff[el] + atomicAdd(&ecur[el], 1);
    nbe[p] = n;
}

// ---------- window scheduler: LPT order of 512 natural + 512 nbe windows ----------
// counting sort desc by window weight (sum of clamped degrees of its 16 nodes)
__global__ __launch_bounds__(1024) void k_sched(
    const int* __restrict__ deg, const int* __restrict__ nbe,
    int* __restrict__ widn, int* __restrict__ wide)
{
    __shared__ int hist[2][128];
    __shared__ int offs[2][128];
    int t = threadIdx.x;
    int half = t >> 9, wi = t & 511;
    if (t < 256) { hist[0][t & 127] = 0; hist[1][t & 127] = 0; }
    __syncthreads();
    int wt = 0;
    for (int k = 0; k < 16; k++) {
        int n = half ? nbe[wi*16 + k] : (wi*16 + k);
        wt += min(deg[n], CAP);
    }
    int key = 127 - min(wt, 127);   // heavy first
    atomicAdd(&hist[half][key], 1);
    __syncthreads();
    if (t < 2) {
        int r = 0;
        for (int k = 0; k < 128; k++) { offs[t][k] = r; r += hist[t][k]; hist[t][k] = 0; }
    }
    __syncthreads();
    int pos = offs[half][key] + atomicAdd(&hist[half][key], 1);
    if (half) wide[pos] = wi; else widn[pos] = wi;
}

// ---------- layer-0 forward: wave = 4 element-sorted nodes; LPT windows; stores A0 ----------
__global__ __launch_bounds__(256) void k_fwd0(
    const float* __restrict__ PK, const int* __restrict__ SSND,
    const float* __restrict__ Wrad0, const float* __restrict__ Wprod0,
    const float* __restrict__ h0, const float* __restrict__ attrs,
    const int* __restrict__ elem, const int* __restrict__ deg,
    const int* __restrict__ nbe, const int* __restrict__ wide,
    float* __restrict__ h1, float* __restrict__ A0)
{
    __shared__ __align__(16) float sB[4][1024];
    __shared__ __align__(16) float sPK[4][MAXST*24];
    __shared__ int sS[4][MAXST];
    int t = threadIdx.x, c = t & 63, w = t >> 6;
    int win = wide[blockIdx.x];
    float wr[8];
#pragma unroll
    for (int nb = 0; nb < 8; nb++) wr[nb] = Wrad0[nb*CC+c];
    int nid[4], nel[4]; float na[4];
#pragma unroll
    for (int g = 0; g < 4; g++) {
        int n = nbe[win*16 + w*4 + g];
        nid[g] = n;
        int el = elem[n]; nel[g] = el; na[g] = attrs[n*NEL+el];
        float acc[NLM];
#pragma unroll
        for (int lm = 0; lm < NLM; lm++) acc[lm] = 0.f;
        int beg = n*CAP, end = beg + min(deg[n], CAP);
        for (int base = beg; base < end; base += MAXST) {
            int m = min(MAXST, end - base);
            stage_pack(PK, SSND, base, m, c, sPK[w], sS[w]);
            for (int cb = 0; cb < m; cb += 4) {
                float hb[4];
#pragma unroll
                for (int k = 0; k < 4; k++)
                    hb[k] = (cb+k < m) ? h0[(size_t)sS[w][cb+k]*CC + c] : 0.f;
#pragma unroll
                for (int jj = 0; jj < 4; jj++) {
                    if (cb+jj >= m) break;
                    const float* rec = &sPK[w][(cb+jj)*24];
                    float wv = 0.f;
#pragma unroll
                    for (int nb = 0; nb < 8; nb++) wv += rec[16+nb]*wr[nb];
                    float tt = wv * hb[jj];
#pragma unroll
                    for (int lm = 0; lm < NLM; lm++) acc[lm] += rec[lm]*tt;
                }
            }
            __builtin_amdgcn_wave_barrier();
        }
#pragma unroll
        for (int lm = 0; lm < NLM; lm++) A0[(size_t)nid[g]*1024 + lm*64 + c] = acc[lm];
        float b0 = acc[0]*acc[0];
        float b1 = acc[1]*acc[1] + acc[2]*acc[2] + acc[3]*acc[3];
        float b2 = acc[4]*acc[4] + acc[5]*acc[5] + acc[6]*acc[6] + acc[7]*acc[7] + acc[8]*acc[8];
        float b3 = 0.f;
#pragma unroll
        for (int lm = 9; lm < 16; lm++) b3 += acc[lm]*acc[lm];
        sB[w][g*256 + 0*64 + c] = b0;
        sB[w][g*256 + 1*64 + c] = b1;
        sB[w][g*256 + 2*64 + c] = b2;
        sB[w][g*256 + 3*64 + c] = b3;
    }
    __builtin_amdgcn_wave_barrier();
    float hv[4] = {0.f, 0.f, 0.f, 0.f};
    int done = 0;
    while (done != 0xF) {
        int g0 = __ffs(~done & 0xF) - 1;
        int el = (g0==0) ? nel[0] : (g0==1) ? nel[1] : (g0==2) ? nel[2] : nel[3];
        int msk = 0;
#pragma unroll
        for (int g = 0; g < 4; g++) if (nel[g] == el) msk |= 1 << g;
        const float* Wn = Wprod0 + (size_t)el*256*CC;
        float tmp[4] = {0.f, 0.f, 0.f, 0.f};
        for (int f4 = 0; f4 < 64; f4++) {
            float wv0 = Wn[(f4*4+0)*CC + c];
            float wv1 = Wn[(f4*4+1)*CC + c];
            float wv2 = Wn[(f4*4+2)*CC + c];
            float wv3 = Wn[(f4*4+3)*CC + c];
#pragma unroll
            for (int g = 0; g < 4; g++) {
                float4 b = *((const float4*)&sB[w][g*256 + f4*4]);
                tmp[g] += b.x*wv0 + b.y*wv1 + b.z*wv2 + b.w*wv3;
            }
        }
#pragma unroll
        for (int g = 0; g < 4; g++) if ((msk >> g) & 1) hv[g] = tmp[g];
        done |= msk;
    }
#pragma unroll
    for (int g = 0; g < 4; g++) h1[(size_t)nid[g]*CC + c] = na[g]*hv[g];
}

// ---------- layer-1 fused fwd+bwd: natural windows in LPT order + e0 folded ----------
__global__ __launch_bounds__(256) void k_fbwd1(
    const float* __restrict__ PK, const int* __restrict__ SSND,
    const float* __restrict__ Wrad1, const float* __restrict__ h1,
    const float* __restrict__ vb1,
    const float* __restrict__ attrs, const float* __restrict__ aew,
    const int* __restrict__ elem,
    const int* __restrict__ batch, const int* __restrict__ deg,
    const int* __restrict__ widn,
    float* __restrict__ gYp, float* __restrict__ gRp, float* __restrict__ gh,
    float* __restrict__ out)
{
    __shared__ __align__(16) float wrls[8*68];
    __shared__ __align__(16) float sPK[4][MAXST*24];
    __shared__ int sS[4][MAXST];
    __shared__ __align__(16) float Mls[4][16*68];
    __shared__ __align__(16) float Tls[4][4*68];
    __shared__ __align__(16) float Gls[4][4*68];
    int t = threadIdx.x, c = t & 63, w = t >> 6;
    int win = widn[blockIdx.x];
    float wr[8];
#pragma unroll
    for (int nb = 0; nb < 8; nb++) wr[nb] = Wrad1[nb*CC+c];
    if (w == 0) {
#pragma unroll
        for (int nb = 0; nb < 8; nb++) wrls[nb*68+c] = wr[nb];
    }
    __syncthreads();
    float esum = 0.f; int curb = -1;
    for (int g = 0; g < 4; g++) {
        int n = win*16 + w*4 + g;
        int el = elem[n];
        float a = attrs[n*NEL+el];
        float g4[4];
#pragma unroll
        for (int l = 0; l < 4; l++) g4[l] = a * vb1[el*256 + l*64 + c];
        int beg = n*CAP, end = beg + min(deg[n], CAP);
        int cnt = end - beg;
        // phase A: recompute A1
        float acc[NLM];
#pragma unroll
        for (int lm = 0; lm < NLM; lm++) acc[lm] = 0.f;
        for (int base = beg; base < end; base += MAXST) {
            int m = min(MAXST, end - base);
            stage_pack(PK, SSND, base, m, c, sPK[w], sS[w]);
            for (int cb = 0; cb < m; cb += 4) {
                float hb[4];
#pragma unroll
                for (int k = 0; k < 4; k++)
                    hb[k] = (cb+k < m) ? h1[(size_t)sS[w][cb+k]*CC + c] : 0.f;
#pragma unroll
                for (int jj = 0; jj < 4; jj++) {
                    if (cb+jj >= m) break;
                    const float* rec = &sPK[w][(cb+jj)*24];
                    float wv = 0.f;
#pragma unroll
                    for (int nb = 0; nb < 8; nb++) wv += rec[16+nb]*wr[nb];
                    float tt = wv * hb[jj];
#pragma unroll
                    for (int lm = 0; lm < NLM; lm++) acc[lm] += rec[lm]*tt;
                }
            }
            __builtin_amdgcn_wave_barrier();
        }
        bool cached = (cnt <= MAXST);
        // energy (+ e0 folded)
        float b0 = acc[0]*acc[0];
        float b1 = acc[1]*acc[1] + acc[2]*acc[2] + acc[3]*acc[3];
        float b2 = acc[4]*acc[4] + acc[5]*acc[5] + acc[6]*acc[6] + acc[7]*acc[7] + acc[8]*acc[8];
        float b3 = 0.f;
#pragma unroll
        for (int lm = 9; lm < 16; lm++) b3 += acc[lm]*acc[lm];
        float ep = b0*vb1[el*256+c] + b1*vb1[el*256+64+c]
                 + b2*vb1[el*256+128+c] + b3*vb1[el*256+192+c];
#pragma unroll
        for (int o = 32; o > 0; o >>= 1) ep += __shfl_xor(ep, o, 64);
        float e0 = 0.f;
        for (int k = 0; k < NEL; k++) e0 += attrs[n*NEL+k] * aew[k];
        int b = batch[n];
        if (b != curb) {
            if (curb >= 0 && c == 0) atomicAdd(&out[curb], esum);
            curb = b; esum = 0.f;
        }
        esum += a * ep + e0;
        float M[NLM];
#pragma unroll
        for (int lm = 0; lm < NLM; lm++) {
            M[lm] = 2.f * acc[lm] * g4[lm_l(lm)];
            Mls[w][lm*68+c] = M[lm];
        }
        __builtin_amdgcn_wave_barrier();
        // phase B
        for (int base = beg; base < end; base += MAXST) {
            int m = min(MAXST, end - base);
            if (!cached) stage_pack(PK, SSND, base, m, c, sPK[w], sS[w]);
            for (int cb = 0; cb < m; cb += 4) {
                int ncq = min(4, m - cb);
                float hb[4];
#pragma unroll
                for (int k = 0; k < 4; k++)
                    hb[k] = (cb+k < m) ? h1[(size_t)sS[w][cb+k]*CC + c] : 0.f;
#pragma unroll
                for (int jj = 0; jj < 4; jj++) {
                    if (jj >= ncq) break;
                    const float* rec = &sPK[w][(cb+jj)*24];
                    float wv = 0.f;
#pragma unroll
                    for (int nb = 0; nb < 8; nb++) wv += rec[16+nb]*wr[nb];
                    float hvv = hb[jj];
                    float my = 0.f;
#pragma unroll
                    for (int lm = 0; lm < NLM; lm++) my += M[lm]*rec[lm];
                    Tls[w][jj*68+c] = wv * hvv;
                    Gls[w][jj*68+c] = hvv * my;
                    atomicAdd(&gh[(size_t)sS[w][cb+jj]*CC + c], wv * my);
                }
                __builtin_amdgcn_wave_barrier();
                {
                    int jj = c >> 4, lm = c & 15;
                    if (jj < ncq) {
                        const float4* mrow = (const float4*)&Mls[w][lm*68];
                        const float4* trow = (const float4*)&Tls[w][jj*68];
                        float s_ = 0.f;
#pragma unroll
                        for (int k4 = 0; k4 < 16; k4++) {
                            float4 mm = mrow[k4]; float4 tv = trow[k4];
                            s_ += mm.x*tv.x + mm.y*tv.y + mm.z*tv.z + mm.w*tv.w;
                        }
                        gYp[(size_t)(base + cb + jj)*16+lm] = s_;
                    }
                }
                if (c < 32) {
                    int jj = c >> 3, nb = c & 7;
                    if (jj < ncq) {
                        const float4* wrow = (const float4*)&wrls[nb*68];
                        const float4* grow = (const float4*)&Gls[w][jj*68];
                        float s_ = 0.f;
#pragma unroll
                        for (int k4 = 0; k4 < 16; k4++) {
                            float4 wv4 = wrow[k4]; float4 gv = grow[k4];
                            s_ += wv4.x*gv.x + wv4.y*gv.y + wv4.z*gv.z + wv4.w*gv.w;
                        }
                        gRp[(size_t)(base + cb + jj)*8+nb] = s_;
                    }
                }
                __builtin_amdgcn_wave_barrier();
            }
        }
    }
    if (curb >= 0 && c == 0) atomicAdd(&out[curb], esum);
}

// ---------- layer-0 backward + inline gseed + inline geometry backward/forces ----------
__global__ __launch_bounds__(256) void k_fbwd0geo(
    const float* __restrict__ PK, const int* __restrict__ SSND,
    const float* __restrict__ Wrad0, const float* __restrict__ h0,
    const float* __restrict__ gh1, const float* __restrict__ Wprod0,
    const float* __restrict__ A0,
    const float* __restrict__ attrs, const int* __restrict__ elem,
    const int* __restrict__ deg, const int* __restrict__ nbe,
    const int* __restrict__ wide,
    const float* __restrict__ gYp, const float* __restrict__ gRp,
    const float* __restrict__ UL, float* __restrict__ F)
{
    __shared__ __align__(16) float wrls[8*68];
    __shared__ __align__(16) float sPK[4][MAXST*24];
    __shared__ int sS[4][MAXST];
    __shared__ __align__(16) float Mls[4][16*68];
    __shared__ __align__(16) float Tls[4][4*68];
    __shared__ __align__(16) float Gls[4][4*68];
    __shared__ __align__(16) float sgh[4][4][64];
    __shared__ float gols[4][4*24];
    int t = threadIdx.x, c = t & 63, w = t >> 6;
    int win = wide[blockIdx.x];
    float wr[8];
#pragma unroll
    for (int nb = 0; nb < 8; nb++) wr[nb] = Wrad0[nb*CC+c];
    if (w == 0) {
#pragma unroll
        for (int nb = 0; nb < 8; nb++) wrls[nb*68+c] = wr[nb];
    }
    __syncthreads();
    int nid[4], nel[4]; float na[4];
#pragma unroll
    for (int g = 0; g < 4; g++) {
        int n = nbe[win*16 + w*4 + g];
        nid[g] = n;
        int el = elem[n]; nel[g] = el; na[g] = attrs[n*NEL+el];
        sgh[w][g][c] = gh1[(size_t)n*CC + c];
    }
    __builtin_amdgcn_wave_barrier();
    float outv[4][4];
    int done = 0;
    while (done != 0xF) {
        int g0 = __ffs(~done & 0xF) - 1;
        int el = (g0==0) ? nel[0] : (g0==1) ? nel[1] : (g0==2) ? nel[2] : nel[3];
        int msk = 0;
#pragma unroll
        for (int g = 0; g < 4; g++) if (nel[g] == el) msk |= 1 << g;
        const float* W0 = Wprod0 + (size_t)el*256*CC;
#pragma unroll
        for (int l = 0; l < 4; l++) {
            const float4* row = (const float4*)(W0 + (size_t)(l*64 + c)*CC);
            float t4[4] = {0.f, 0.f, 0.f, 0.f};
#pragma unroll 4
            for (int k4 = 0; k4 < 16; k4++) {
                float4 wv = row[k4];
#pragma unroll
                for (int g = 0; g < 4; g++) {
                    float4 gg = *((const float4*)&sgh[w][g][k4*4]);
                    t4[g] += wv.x*gg.x + wv.y*gg.y + wv.z*gg.z + wv.w*gg.w;
                }
            }
#pragma unroll
            for (int g = 0; g < 4; g++) if ((msk >> g) & 1) outv[l][g] = t4[g];
        }
        done |= msk;
    }
    for (int g = 0; g < 4; g++) {
        int n = nid[g];
        float g4[4];
#pragma unroll
        for (int l = 0; l < 4; l++) g4[l] = na[g]*outv[l][g];
        int beg = n*CAP, end = beg + min(deg[n], CAP);
        float acc[NLM];
#pragma unroll
        for (int lm = 0; lm < NLM; lm++) acc[lm] = A0[(size_t)n*1024 + lm*64 + c];
        float M[NLM];
#pragma unroll
        for (int lm = 0; lm < NLM; lm++) {
            M[lm] = 2.f * acc[lm] * g4[lm_l(lm)];
            Mls[w][lm*68+c] = M[lm];
        }
        __builtin_amdgcn_wave_barrier();
        for (int base = beg; base < end; base += MAXST) {
            int m = min(MAXST, end - base);
            stage_pack(PK, SSND, base, m, c, sPK[w], sS[w]);
            for (int cb = 0; cb < m; cb += 4) {
                int ncq = min(4, m - cb);
                float hb[4];
#pragma unroll
                for (int k = 0; k < 4; k++)
                    hb[k] = (cb+k < m) ? h0[(size_t)sS[w][cb+k]*CC + c] : 0.f;
#pragma unroll
                for (int jj = 0; jj < 4; jj++) {
                    if (jj >= ncq) break;
                    const float* rec = &sPK[w][(cb+jj)*24];
                    float wv = 0.f;
#pragma unroll
                    for (int nb = 0; nb < 8; nb++) wv += rec[16+nb]*wr[nb];
                    float hvv = hb[jj];
                    float my = 0.f;
#pragma unroll
                    for (int lm = 0; lm < NLM; lm++) my += M[lm]*rec[lm];
                    Tls[w][jj*68+c] = wv * hvv;
                    Gls[w][jj*68+c] = hvv * my;
                }
                __builtin_amdgcn_wave_barrier();
                {
                    int jj = c >> 4, lm = c & 15;
                    if (jj < ncq) {
                        const float4* mrow = (const float4*)&Mls[w][lm*68];
                        const float4* trow = (const float4*)&Tls[w][jj*68];
                        float s_ = 0.f;
#pragma unroll
                        for (int k4 = 0; k4 < 16; k4++) {
                            float4 mm = mrow[k4]; float4 tv = trow[k4];
                            s_ += mm.x*tv.x + mm.y*tv.y + mm.z*tv.z + mm.w*tv.w;
                        }
                        gols[w][jj*24+lm] = s_ + gYp[(size_t)(base + cb + jj)*16+lm];
                    }
                }
                if (c < 32) {
                    int jj = c >> 3, nb = c & 7;
                    if (jj < ncq) {
                        const float4* wrow = (const float4*)&wrls[nb*68];
                        const float4* grow = (const float4*)&Gls[w][jj*68];
                        float s_ = 0.f;
#pragma unroll
                        for (int k4 = 0; k4 < 16; k4++) {
                            float4 wv4 = wrow[k4]; float4 gv = grow[k4];
                            s_ += wv4.x*gv.x + wv4.y*gv.y + wv4.z*gv.z + wv4.w*gv.w;
                        }
                        gols[w][jj*24+16+nb] = s_ + gRp[(size_t)(base + cb + jj)*8+nb];
                    }
                }
                __builtin_amdgcn_wave_barrier();
                if ((c & 15) == 0) {
                    int jj = c >> 4;
                    if (jj < ncq) {
                        int pp = base + cb + jj;
                        const float* go = &gols[w][jj*24];
                        float4 ul = ((const float4*)UL)[pp];
                        float x = ul.x, y = ul.y, z = ul.z, len = ul.w;
                        float x2 = x*x, y2 = y*y, z2 = z*z;
                        float gx = 0.f, gy = 0.f, gz = 0.f;
                        gx += 0.4886025119029199f*go[3];
                        gy += 0.4886025119029199f*go[1];
                        gz += 0.4886025119029199f*go[2];
                        gx += 1.0925484305920792f*y*go[4];  gy += 1.0925484305920792f*x*go[4];
                        gy += 1.0925484305920792f*z*go[5];  gz += 1.0925484305920792f*y*go[5];
                        gz += 1.8923493915151203f*z*go[6];
                        gx += 1.0925484305920792f*z*go[7];  gz += 1.0925484305920792f*x*go[7];
                        gx += 1.0925484305920792f*x*go[8];  gy -= 1.0925484305920792f*y*go[8];
                        gx += 3.540261539559861f*x*y*go[9];
                        gy += 0.5900435899266435f*(3.f*x2 - 3.f*y2)*go[9];
                        gx += 2.890611442640554f*y*z*go[10]; gy += 2.890611442640554f*x*z*go[10]; gz += 2.890611442640554f*x*y*go[10];
                        gy += 0.4570457994644658f*(5.f*z2 - 1.f)*go[11]; gz += 4.570457994644658f*y*z*go[11];
                        gz += 0.3731763325901154f*(15.f*z2 - 3.f)*go[12];
                        gx += 0.4570457994644658f*(5.f*z2 - 1.f)*go[13]; gz += 4.570457994644658f*x*z*go[13];
                        gx += 2.890611442640554f*x*z*go[14]; gy -= 2.890611442640554f*y*z*go[14];
                        gz += 1.445305721320277f*(x2 - y2)*go[14];
                        gx += 0.5900435899266435f*(3.f*x2 - 3.f*y2)*go[15];
                        gy -= 3.540261539559861f*x*y*go[15];
                        float ur = len * 0.2f;
                        float u2 = ur*ur, u4 = u2*u2, u5 = u4*ur, u6 = u5*ur, u7 = u6*ur;
                        float poly  = 1.f - 21.f*u5 + 35.f*u6 - 15.f*u7;
                        float dpoly = (-105.f*u4 + 210.f*u5 - 105.f*u6)*0.2f;
                        const float s2f = 0.632455532033676f;
                        const float k1 = PI_F/5.f;
                        float th = k1*len;
                        float s1, c1; sincosf(th, &s1, &c1);
                        float sn_ = s1, cs = c1;
                        float inv_r = 1.f/len;
                        bool tiny = (len < 2e-3f);
                        float gL = 0.f;
#pragma unroll
                        for (int nb = 0; nb < 8; nb++) {
                            float kn = k1*(float)(nb+1);
                            float bes = s2f*sn_*inv_r;
                            float dbes;
                            if (tiny) dbes = -s2f*kn*kn*kn*len*(1.f/3.f);
                            else      dbes = s2f*(kn*cs - sn_*inv_r)*inv_r;
                            gL += go[16+nb]*(dbes*poly + bes*dpoly);
                            float ns = sn_*c1 + cs*s1;
                            float nc = cs*c1 - sn_*s1;
                            sn_ = ns; cs = nc;
                        }
                        float dot = gx*x + gy*y + gz*z;
                        float gvx = (gx - dot*x)*inv_r + gL*x;
                        float gvy = (gy - dot*y)*inv_r + gL*y;
                        float gvz = (gz - dot*z)*inv_r + gL*z;
                        int sn2 = sS[w][cb+jj];
                        atomicAdd(&F[n*3+0], -gvx);
                        atomicAdd(&F[n*3+1], -gvy);
                        atomicAdd(&F[n*3+2], -gvz);
                        atomicAdd(&F[sn2*3+0],  gvx);
                        atomicAdd(&F[sn2*3+1],  gvy);
                        atomicAdd(&F[sn2*3+2],  gvz);
                    }
                }
                __builtin_amdgcn_wave_barrier();
            }
        }
    }
}

extern "C" void kernel_launch(void* const* d_in, const int* in_sizes, int n_in,
                              void* d_out, int out_size, void* d_ws, size_t ws_size,
                              hipStream_t stream)
{
    const float* positions  = (const float*)d_in[0];
    const float* node_attrs = (const float*)d_in[1];
    const float* shifts     = (const float*)d_in[2];
    const float* W_embed    = (const float*)d_in[3];
    const float* aew        = (const float*)d_in[4];
    const float* W_rad      = (const float*)d_in[5];
    const float* W_prod     = (const float*)d_in[6];
    const float* w_read     = (const float*)d_in[7];
    const int*   edge_index = (const int*)d_in[8];
    const int*   batch      = (const int*)d_in[9];
    float* out = (float*)d_out;

    const int* snd = edge_index;
    const int* rcv = edge_index + NE;

    char* ws = (char*)d_ws;
    size_t off = 0;
    auto allocf = [&](size_t nelems) -> float* {
        float* p = (float*)(ws + off); off += nelems * sizeof(float); return p;
    };
    float* PK   = allocf((size_t)NN*CAP*24);
    float* UL   = allocf((size_t)NN*CAP*4);
    float* H0   = allocf((size_t)NN*CC);
    float* H1   = allocf((size_t)NN*CC);
    float* A0   = allocf((size_t)NN*1024);
    float* GYP  = allocf((size_t)NN*CAP*16);
    float* GRP  = allocf((size_t)NN*CAP*8);
    float* VB1  = allocf((size_t)NEL*256);
    float* GH1  = allocf((size_t)NN*CC);      // zeroed in k_nbe
    // --- contiguous zero region: CUR + ECNT + ECUR ---
    size_t zero_off = off;
    int* CUR   = (int*)(ws + off); off += (size_t)NN*4;
    int* ECNT  = (int*)(ws + off); off += 16*4;
    int* ECUR  = (int*)(ws + off); off += 16*4;
    size_t zero_bytes = off - zero_off;
    // --- rest ---
    int* ELEM  = (int*)(ws + off); off += (size_t)NN*4;
    int* SSND  = (int*)(ws + off); off += (size_t)NN*CAP*4;
    int* ELOFF = (int*)(ws + off); off += 16*4;
    int* NBE   = (int*)(ws + off); off += (size_t)NN*4;
    int* WIDN  = (int*)(ws + off); off += NWIN*4;
    int* WIDE  = (int*)(ws + off); off += NWIN*4;

    hipMemsetAsync(ws + zero_off, 0, zero_bytes, stream);

    const float* Wrad0  = W_rad;
    const float* Wrad1  = W_rad + 8*CC;
    const float* Wprod0 = W_prod;
    const float* Wprod1 = W_prod + (size_t)NEL*256*CC;

    k_front<<<256 + 512 + NEL, 256, 0, stream>>>(
        positions, shifts, snd, rcv, CUR, PK, SSND, UL,
        node_attrs, W_embed, H0, ELEM, ECNT, Wprod1, w_read, VB1);
    k_escan<<<1, 64, 0, stream>>>(ECNT, ELOFF);
    k_nbe<<<NN/256, 256, 0, stream>>>(ELEM, ELOFF, ECUR, NBE, GH1, out);
    k_sched<<<1, 1024, 0, stream>>>(CUR, NBE, WIDN, WIDE);

    k_fwd0<<<NWIN, 256, 0, stream>>>(PK, SSND, Wrad0, Wprod0, H0, node_attrs, ELEM,
                                     CUR, NBE, WIDE, H1, A0);
    k_fbwd1<<<NWIN, 256, 0, stream>>>(PK, SSND, Wrad1, H1, VB1, node_attrs, aew, ELEM,
                                      batch, CUR, WIDN, GYP, GRP, GH1, out);
    k_fbwd0geo<<<NWIN, 256, 0, stream>>>(PK, SSND, Wrad0, H0, GH1, Wprod0, A0,
                                         node_attrs, ELEM, CUR, NBE, WIDE,
                                         GYP, GRP, UL, out + NG);
    (void)in_sizes; (void)n_in; (void)out_size; (void)ws_size;
}

// Round 20
// 244.788 us; speedup vs baseline: 1.0783x; 1.0783x over previous
//
#include <hip/hip_runtime.h>
#include <math.h>

#define NN 8192
#define NE 65536
#define NG 16
#define NEL 10
#define CC 64
#define NLM 16
#define MAXST 32
#define PI_F 3.14159265358979f

__device__ __forceinline__ int lm_l(int lm) {
    return (lm == 0) ? 0 : (lm < 4) ? 1 : (lm < 9) ? 2 : 3;
}

// stage cnt packed records (24 floats each) + sender ids into per-wave LDS, coalesced
__device__ __forceinline__ void stage_pack(
    const float* __restrict__ PK, const int* __restrict__ SSND,
    int beg, int cnt, int c, float* sPK, int* sS)
{
    int tot = cnt * 24;
    for (int i = c; i < tot; i += 64) sPK[i] = PK[(size_t)beg*24 + i];
    if (c < cnt) sS[c] = SSND[beg + c];
    __builtin_amdgcn_wave_barrier();
}

// ---------- fused front: blocks [0,256) geom | [256,768) h0/elem | [768,778) vb1 ----------
__global__ __launch_bounds__(256) void k_front(
    const float* __restrict__ pos, const float* __restrict__ shifts,
    const int* __restrict__ snd, const int* __restrict__ rcv,
    float* __restrict__ Y, float* __restrict__ R,
    float* __restrict__ U, float* __restrict__ L, int* __restrict__ cnt,
    const float* __restrict__ attrs, const float* __restrict__ Wemb,
    float* __restrict__ h0, int* __restrict__ elem,
    const float* __restrict__ Wprod1, const float* __restrict__ wread,
    float* __restrict__ vb1)
{
    int bx = blockIdx.x;
    if (bx < 256) {
        int e = bx * 256 + threadIdx.x;
        int s = snd[e], r = rcv[e];
        float vx = pos[r*3+0] - pos[s*3+0] + shifts[e*3+0];
        float vy = pos[r*3+1] - pos[s*3+1] + shifts[e*3+1];
        float vz = pos[r*3+2] - pos[s*3+2] + shifts[e*3+2];
        float len = sqrtf(vx*vx + vy*vy + vz*vz + 1e-9f);
        L[e] = len;
        if (len >= 5.0f) return;   // cut==0 AND d(cut*bessel)/dr==0: exactly zero fwd+bwd
        atomicAdd(&cnt[r], 1);
        float x = vx/len, y = vy/len, z = vz/len;
        U[e*3+0] = x; U[e*3+1] = y; U[e*3+2] = z;
        float x2 = x*x, y2 = y*y, z2 = z*z;
        float4* Yv = (float4*)(Y + (size_t)e*16);
        Yv[0] = make_float4(0.28209479177387814f,
                            0.4886025119029199f*y,
                            0.4886025119029199f*z,
                            0.4886025119029199f*x);
        Yv[1] = make_float4(1.0925484305920792f*x*y,
                            1.0925484305920792f*y*z,
                            0.31539156525252005f*(3.f*z2 - 1.f),
                            1.0925484305920792f*x*z);
        Yv[2] = make_float4(0.5462742152960396f*(x2 - y2),
                            0.5900435899266435f*y*(3.f*x2 - y2),
                            2.890611442640554f*x*y*z,
                            0.4570457994644658f*y*(5.f*z2 - 1.f));
        Yv[3] = make_float4(0.3731763325901154f*z*(5.f*z2 - 3.f),
                            0.4570457994644658f*x*(5.f*z2 - 1.f),
                            1.445305721320277f*z*(x2 - y2),
                            0.5900435899266435f*x*(x2 - 3.f*y2));
        float ur = len * 0.2f;
        float u2 = ur*ur, u4 = u2*u2, u5 = u4*ur, u6 = u5*ur, u7 = u6*ur;
        float cut = 1.f - 21.f*u5 + 35.f*u6 - 15.f*u7;
        const float s2f = 0.632455532033676f;
        float th = (PI_F/5.f) * len;
        float s1, c1; sincosf(th, &s1, &c1);
        float sn_ = s1, cs = c1;
        float coef = s2f * cut / len;
        float rv[8];
#pragma unroll
        for (int nb = 0; nb < 8; nb++) {
            rv[nb] = coef * sn_;
            float ns = sn_*c1 + cs*s1;
            float nc = cs*c1 - sn_*s1;
            sn_ = ns; cs = nc;
        }
        float4* Rv = (float4*)(R + (size_t)e*8);
        Rv[0] = make_float4(rv[0], rv[1], rv[2], rv[3]);
        Rv[1] = make_float4(rv[4], rv[5], rv[6], rv[7]);
    } else if (bx < 768) {
        int t = threadIdx.x, c = t & 63, w = t >> 6;
        for (int g = 0; g < 4; g++) {
            int n = (bx - 256)*16 + w*4 + g;
            float hv = 0.f;
            for (int el = 0; el < NEL; el++) hv += attrs[n*NEL+el] * Wemb[el*CC+c];
            h0[(size_t)n*CC+c] = hv;
            if (c == 0) {
                int el = 0;
                for (int k = 0; k < NEL; k++)
                    if (attrs[n*NEL+k] > 0.5f) el = k;
                elem[n] = el;
            }
        }
    } else {
        int el = bx - 768, f = threadIdx.x;
        float s = 0.f;
        for (int c = 0; c < CC; c++) s += wread[c] * Wprod1[(size_t)el*256*CC + f*CC + c];
        vb1[el*256+f] = s;
    }
}

// ---------- scan (shfl-based) + element histogram/offsets ----------
__global__ __launch_bounds__(1024) void k_scan(
    const int* __restrict__ cnt, int* __restrict__ offs,
    const int* __restrict__ elem, int* __restrict__ eoff)
{
    __shared__ int wsum[16];
    __shared__ int hist[NEL];
    int t = threadIdx.x, lane = t & 63, w = t >> 6;
    if (t < NEL) hist[t] = 0;
    __syncthreads();
    int loc[8];
    int run = 0;
#pragma unroll
    for (int i = 0; i < 8; i++) { int v = cnt[t*8+i]; loc[i] = run; run += v; }
    int v = run;
#pragma unroll
    for (int o = 1; o < 64; o <<= 1) {
        int u = __shfl_up(v, o, 64);
        if (lane >= o) v += u;
    }
    if (lane == 63) wsum[w] = v;
    __syncthreads();
    if (t < 16) {
        int x = wsum[t];
#pragma unroll
        for (int o = 1; o < 16; o <<= 1) {
            int u = __shfl_up(x, o, 64);
            if (t >= o) x += u;
        }
        wsum[t] = x;
    }
    __syncthreads();
    int wpre = (w == 0) ? 0 : wsum[w-1];
    int pre = wpre + v - run;
#pragma unroll
    for (int i = 0; i < 8; i++) offs[t*8+i] = pre + loc[i];
    if (t == 1023) offs[NN] = pre + run;
#pragma unroll
    for (int i = 0; i < 8; i++) atomicAdd(&hist[elem[t*8+i]], 1);
    __syncthreads();
    if (t == 0) {
        int r = 0;
        for (int el = 0; el < NEL; el++) { eoff[el] = r; r += hist[el]; }
        eoff[NEL] = r;
    }
}

// ---------- fused scatter + pack + element node-scatter + GH1/out zeroing ----------
__global__ void k_scatpack(
    const int* __restrict__ snd, const int* __restrict__ rcv,
    const float* __restrict__ Y, const float* __restrict__ R,
    const float* __restrict__ U, const float* __restrict__ L,
    const int* __restrict__ offs, int* __restrict__ cur,
    float* __restrict__ PK, int* __restrict__ SSND,
    float* __restrict__ UL,
    const int* __restrict__ elem, const int* __restrict__ eoff,
    int* __restrict__ ecur, int* __restrict__ nbe,
    float* __restrict__ gh1, float* __restrict__ out)
{
    int e = blockIdx.x * blockDim.x + threadIdx.x;
    {
        float4* g4 = (float4*)gh1;
        g4[e*2+0] = make_float4(0.f, 0.f, 0.f, 0.f);
        g4[e*2+1] = make_float4(0.f, 0.f, 0.f, 0.f);
    }
    if (e < NG + NN*3) out[e] = 0.f;
    if (e < NN) {
        int el = elem[e];
        int p = eoff[el] + atomicAdd(&ecur[el], 1);
        nbe[p] = e;
    }
    if (e >= NE) return;
    if (L[e] >= 5.0f) return;
    int r = rcv[e];
    int p = offs[r] + atomicAdd(&cur[r], 1);
    const float4* Yp = (const float4*)(Y + (size_t)e*16);
    float4* d = (float4*)(PK + (size_t)p*24);
    d[0] = Yp[0]; d[1] = Yp[1]; d[2] = Yp[2]; d[3] = Yp[3];
    const float4* Rp = (const float4*)(R + (size_t)e*8);
    d[4] = Rp[0]; d[5] = Rp[1];
    SSND[p] = snd[e];
    ((float4*)UL)[p] = make_float4(U[e*3+0], U[e*3+1], U[e*3+2], L[e]);
}

// ---------- layer-0 forward: wave = 4 element-sorted nodes; stores A0 ----------
__global__ __launch_bounds__(256) void k_fwd0(
    const float* __restrict__ PK, const int* __restrict__ SSND,
    const float* __restrict__ Wrad0, const float* __restrict__ Wprod0,
    const float* __restrict__ h0, const float* __restrict__ attrs,
    const int* __restrict__ elem, const int* __restrict__ offs,
    const int* __restrict__ nbe, float* __restrict__ h1,
    float* __restrict__ A0)
{
    __shared__ __align__(16) float sB[4][1024];
    __shared__ __align__(16) float sPK[4][MAXST*24];
    __shared__ int sS[4][MAXST];
    int t = threadIdx.x, c = t & 63, w = t >> 6;
    float wr[8];
#pragma unroll
    for (int nb = 0; nb < 8; nb++) wr[nb] = Wrad0[nb*CC+c];
    int nid[4], nel[4]; float na[4];
#pragma unroll
    for (int g = 0; g < 4; g++) {
        int n = nbe[blockIdx.x*16 + w*4 + g];
        nid[g] = n;
        int el = elem[n]; nel[g] = el; na[g] = attrs[n*NEL+el];
        float acc[NLM];
#pragma unroll
        for (int lm = 0; lm < NLM; lm++) acc[lm] = 0.f;
        int beg = offs[n], end = offs[n+1];
        for (int base = beg; base < end; base += MAXST) {
            int m = min(MAXST, end - base);
            stage_pack(PK, SSND, base, m, c, sPK[w], sS[w]);
            for (int cb = 0; cb < m; cb += 4) {
                float hb[4];
#pragma unroll
                for (int k = 0; k < 4; k++)
                    hb[k] = (cb+k < m) ? h0[(size_t)sS[w][cb+k]*CC + c] : 0.f;
#pragma unroll
                for (int jj = 0; jj < 4; jj++) {
                    if (cb+jj >= m) break;
                    const float* rec = &sPK[w][(cb+jj)*24];
                    float wv = 0.f;
#pragma unroll
                    for (int nb = 0; nb < 8; nb++) wv += rec[16+nb]*wr[nb];
                    float tt = wv * hb[jj];
#pragma unroll
                    for (int lm = 0; lm < NLM; lm++) acc[lm] += rec[lm]*tt;
                }
            }
            __builtin_amdgcn_wave_barrier();
        }
#pragma unroll
        for (int lm = 0; lm < NLM; lm++) A0[(size_t)nid[g]*1024 + lm*64 + c] = acc[lm];
        float b0 = acc[0]*acc[0];
        float b1 = acc[1]*acc[1] + acc[2]*acc[2] + acc[3]*acc[3];
        float b2 = acc[4]*acc[4] + acc[5]*acc[5] + acc[6]*acc[6] + acc[7]*acc[7] + acc[8]*acc[8];
        float b3 = 0.f;
#pragma unroll
        for (int lm = 9; lm < 16; lm++) b3 += acc[lm]*acc[lm];
        sB[w][g*256 + 0*64 + c] = b0;
        sB[w][g*256 + 1*64 + c] = b1;
        sB[w][g*256 + 2*64 + c] = b2;
        sB[w][g*256 + 3*64 + c] = b3;
    }
    __builtin_amdgcn_wave_barrier();
    float hv[4] = {0.f, 0.f, 0.f, 0.f};
    int done = 0;
    while (done != 0xF) {
        int g0 = __ffs(~done & 0xF) - 1;
        int el = (g0==0) ? nel[0] : (g0==1) ? nel[1] : (g0==2) ? nel[2] : nel[3];
        int msk = 0;
#pragma unroll
        for (int g = 0; g < 4; g++) if (nel[g] == el) msk |= 1 << g;
        const float* Wn = Wprod0 + (size_t)el*256*CC;
        float tmp[4] = {0.f, 0.f, 0.f, 0.f};
        for (int f4 = 0; f4 < 64; f4++) {
            float wv0 = Wn[(f4*4+0)*CC + c];
            float wv1 = Wn[(f4*4+1)*CC + c];
            float wv2 = Wn[(f4*4+2)*CC + c];
            float wv3 = Wn[(f4*4+3)*CC + c];
#pragma unroll
            for (int g = 0; g < 4; g++) {
                float4 b = *((const float4*)&sB[w][g*256 + f4*4]);
                tmp[g] += b.x*wv0 + b.y*wv1 + b.z*wv2 + b.w*wv3;
            }
        }
#pragma unroll
        for (int g = 0; g < 4; g++) if ((msk >> g) & 1) hv[g] = tmp[g];
        done |= msk;
    }
#pragma unroll
    for (int g = 0; g < 4; g++) h1[(size_t)nid[g]*CC + c] = na[g]*hv[g];
}

// ---------- layer-1 fused fwd+bwd: natural node order + e0 folded ----------
__global__ __launch_bounds__(256) void k_fbwd1(
    const float* __restrict__ PK, const int* __restrict__ SSND,
    const float* __restrict__ Wrad1, const float* __restrict__ h1,
    const float* __restrict__ vb1,
    const float* __restrict__ attrs, const float* __restrict__ aew,
    const int* __restrict__ elem,
    const int* __restrict__ batch, const int* __restrict__ offs,
    float* __restrict__ gYp, float* __restrict__ gRp, float* __restrict__ gh,
    float* __restrict__ out)
{
    __shared__ __align__(16) float wrls[8*68];
    __shared__ __align__(16) float sPK[4][MAXST*24];
    __shared__ int sS[4][MAXST];
    __shared__ __align__(16) float Mls[4][16*68];
    __shared__ __align__(16) float Tls[4][4*68];
    __shared__ __align__(16) float Gls[4][4*68];
    int t = threadIdx.x, c = t & 63, w = t >> 6;
    float wr[8];
#pragma unroll
    for (int nb = 0; nb < 8; nb++) wr[nb] = Wrad1[nb*CC+c];
    if (w == 0) {
#pragma unroll
        for (int nb = 0; nb < 8; nb++) wrls[nb*68+c] = wr[nb];
    }
    __syncthreads();
    float esum = 0.f; int curb = -1;
    for (int g = 0; g < 4; g++) {
        int n = blockIdx.x*16 + w*4 + g;
        int el = elem[n];
        float a = attrs[n*NEL+el];
        float g4[4];
#pragma unroll
        for (int l = 0; l < 4; l++) g4[l] = a * vb1[el*256 + l*64 + c];
        int beg = offs[n], end = offs[n+1];
        int cnt = end - beg;
        // phase A: recompute A1
        float acc[NLM];
#pragma unroll
        for (int lm = 0; lm < NLM; lm++) acc[lm] = 0.f;
        for (int base = beg; base < end; base += MAXST) {
            int m = min(MAXST, end - base);
            stage_pack(PK, SSND, base, m, c, sPK[w], sS[w]);
            for (int cb = 0; cb < m; cb += 4) {
                float hb[4];
#pragma unroll
                for (int k = 0; k < 4; k++)
                    hb[k] = (cb+k < m) ? h1[(size_t)sS[w][cb+k]*CC + c] : 0.f;
#pragma unroll
                for (int jj = 0; jj < 4; jj++) {
                    if (cb+jj >= m) break;
                    const float* rec = &sPK[w][(cb+jj)*24];
                    float wv = 0.f;
#pragma unroll
                    for (int nb = 0; nb < 8; nb++) wv += rec[16+nb]*wr[nb];
                    float tt = wv * hb[jj];
#pragma unroll
                    for (int lm = 0; lm < NLM; lm++) acc[lm] += rec[lm]*tt;
                }
            }
            __builtin_amdgcn_wave_barrier();
        }
        bool cached = (cnt <= MAXST);
        // energy (+ e0 folded)
        float b0 = acc[0]*acc[0];
        float b1 = acc[1]*acc[1] + acc[2]*acc[2] + acc[3]*acc[3];
        float b2 = acc[4]*acc[4] + acc[5]*acc[5] + acc[6]*acc[6] + acc[7]*acc[7] + acc[8]*acc[8];
        float b3 = 0.f;
#pragma unroll
        for (int lm = 9; lm < 16; lm++) b3 += acc[lm]*acc[lm];
        float ep = b0*vb1[el*256+c] + b1*vb1[el*256+64+c]
                 + b2*vb1[el*256+128+c] + b3*vb1[el*256+192+c];
#pragma unroll
        for (int o = 32; o > 0; o >>= 1) ep += __shfl_xor(ep, o, 64);
        float e0 = 0.f;
        for (int k = 0; k < NEL; k++) e0 += attrs[n*NEL+k] * aew[k];
        int b = batch[n];
        if (b != curb) {
            if (curb >= 0 && c == 0) atomicAdd(&out[curb], esum);
            curb = b; esum = 0.f;
        }
        esum += a * ep + e0;
        float M[NLM];
#pragma unroll
        for (int lm = 0; lm < NLM; lm++) {
            M[lm] = 2.f * acc[lm] * g4[lm_l(lm)];
            Mls[w][lm*68+c] = M[lm];
        }
        __builtin_amdgcn_wave_barrier();
        // phase B
        for (int base = beg; base < end; base += MAXST) {
            int m = min(MAXST, end - base);
            if (!cached) stage_pack(PK, SSND, base, m, c, sPK[w], sS[w]);
            for (int cb = 0; cb < m; cb += 4) {
                int ncq = min(4, m - cb);
                float hb[4];
#pragma unroll
                for (int k = 0; k < 4; k++)
                    hb[k] = (cb+k < m) ? h1[(size_t)sS[w][cb+k]*CC + c] : 0.f;
#pragma unroll
                for (int jj = 0; jj < 4; jj++) {
                    if (jj >= ncq) break;
                    const float* rec = &sPK[w][(cb+jj)*24];
                    float wv = 0.f;
#pragma unroll
                    for (int nb = 0; nb < 8; nb++) wv += rec[16+nb]*wr[nb];
                    float hvv = hb[jj];
                    float my = 0.f;
#pragma unroll
                    for (int lm = 0; lm < NLM; lm++) my += M[lm]*rec[lm];
                    Tls[w][jj*68+c] = wv * hvv;
                    Gls[w][jj*68+c] = hvv * my;
                    atomicAdd(&gh[(size_t)sS[w][cb+jj]*CC + c], wv * my);
                }
                __builtin_amdgcn_wave_barrier();
                {
                    int jj = c >> 4, lm = c & 15;
                    if (jj < ncq) {
                        const float4* mrow = (const float4*)&Mls[w][lm*68];
                        const float4* trow = (const float4*)&Tls[w][jj*68];
                        float s_ = 0.f;
#pragma unroll
                        for (int k4 = 0; k4 < 16; k4++) {
                            float4 mm = mrow[k4]; float4 tv = trow[k4];
                            s_ += mm.x*tv.x + mm.y*tv.y + mm.z*tv.z + mm.w*tv.w;
                        }
                        gYp[(size_t)(base + cb + jj)*16+lm] = s_;
                    }
                }
                if (c < 32) {
                    int jj = c >> 3, nb = c & 7;
                    if (jj < ncq) {
                        const float4* wrow = (const float4*)&wrls[nb*68];
                        const float4* grow = (const float4*)&Gls[w][jj*68];
                        float s_ = 0.f;
#pragma unroll
                        for (int k4 = 0; k4 < 16; k4++) {
                            float4 wv4 = wrow[k4]; float4 gv = grow[k4];
                            s_ += wv4.x*gv.x + wv4.y*gv.y + wv4.z*gv.z + wv4.w*gv.w;
                        }
                        gRp[(size_t)(base + cb + jj)*8+nb] = s_;
                    }
                }
                __builtin_amdgcn_wave_barrier();
            }
        }
    }
    if (curb >= 0 && c == 0) atomicAdd(&out[curb], esum);
}

// ---------- layer-0 backward + inline gseed + inline geometry backward/forces ----------
__global__ __launch_bounds__(256) void k_fbwd0geo(
    const float* __restrict__ PK, const int* __restrict__ SSND,
    const float* __restrict__ Wrad0, const float* __restrict__ h0,
    const float* __restrict__ gh1, const float* __restrict__ Wprod0,
    const float* __restrict__ A0,
    const float* __restrict__ attrs, const int* __restrict__ elem,
    const int* __restrict__ offs, const int* __restrict__ nbe,
    const float* __restrict__ gYp, const float* __restrict__ gRp,
    const float* __restrict__ UL, float* __restrict__ F)
{
    __shared__ __align__(16) float wrls[8*68];
    __shared__ __align__(16) float sPK[4][MAXST*24];
    __shared__ int sS[4][MAXST];
    __shared__ __align__(16) float Mls[4][16*68];
    __shared__ __align__(16) float Tls[4][4*68];
    __shared__ __align__(16) float Gls[4][4*68];
    __shared__ __align__(16) float sgh[4][4][64];
    __shared__ float gols[4][4*24];
    int t = threadIdx.x, c = t & 63, w = t >> 6;
    float wr[8];
#pragma unroll
    for (int nb = 0; nb < 8; nb++) wr[nb] = Wrad0[nb*CC+c];
    if (w == 0) {
#pragma unroll
        for (int nb = 0; nb < 8; nb++) wrls[nb*68+c] = wr[nb];
    }
    __syncthreads();
    int nid[4], nel[4]; float na[4];
#pragma unroll
    for (int g = 0; g < 4; g++) {
        int n = nbe[blockIdx.x*16 + w*4 + g];
        nid[g] = n;
        int el = elem[n]; nel[g] = el; na[g] = attrs[n*NEL+el];
        sgh[w][g][c] = gh1[(size_t)n*CC + c];
    }
    __builtin_amdgcn_wave_barrier();
    float outv[4][4];
    int done = 0;
    while (done != 0xF) {
        int g0 = __ffs(~done & 0xF) - 1;
        int el = (g0==0) ? nel[0] : (g0==1) ? nel[1] : (g0==2) ? nel[2] : nel[3];
        int msk = 0;
#pragma unroll
        for (int g = 0; g < 4; g++) if (nel[g] == el) msk |= 1 << g;
        const float* W0 = Wprod0 + (size_t)el*256*CC;
#pragma unroll
        for (int l = 0; l < 4; l++) {
            const float4* row = (const float4*)(W0 + (size_t)(l*64 + c)*CC);
            float t4[4] = {0.f, 0.f, 0.f, 0.f};
#pragma unroll 4
            for (int k4 = 0; k4 < 16; k4++) {
                float4 wv = row[k4];
#pragma unroll
                for (int g = 0; g < 4; g++) {
                    float4 gg = *((const float4*)&sgh[w][g][k4*4]);
                    t4[g] += wv.x*gg.x + wv.y*gg.y + wv.z*gg.z + wv.w*gg.w;
                }
            }
#pragma unroll
            for (int g = 0; g < 4; g++) if ((msk >> g) & 1) outv[l][g] = t4[g];
        }
        done |= msk;
    }
    for (int g = 0; g < 4; g++) {
        int n = nid[g];
        float g4[4];
#pragma unroll
        for (int l = 0; l < 4; l++) g4[l] = na[g]*outv[l][g];
        int beg = offs[n], end = offs[n+1];
        float acc[NLM];
#pragma unroll
        for (int lm = 0; lm < NLM; lm++) acc[lm] = A0[(size_t)n*1024 + lm*64 + c];
        float M[NLM];
#pragma unroll
        for (int lm = 0; lm < NLM; lm++) {
            M[lm] = 2.f * acc[lm] * g4[lm_l(lm)];
            Mls[w][lm*68+c] = M[lm];
        }
        __builtin_amdgcn_wave_barrier();
        for (int base = beg; base < end; base += MAXST) {
            int m = min(MAXST, end - base);
            stage_pack(PK, SSND, base, m, c, sPK[w], sS[w]);
            for (int cb = 0; cb < m; cb += 4) {
                int ncq = min(4, m - cb);
                float hb[4];
#pragma unroll
                for (int k = 0; k < 4; k++)
                    hb[k] = (cb+k < m) ? h0[(size_t)sS[w][cb+k]*CC + c] : 0.f;
#pragma unroll
                for (int jj = 0; jj < 4; jj++) {
                    if (jj >= ncq) break;
                    const float* rec = &sPK[w][(cb+jj)*24];
                    float wv = 0.f;
#pragma unroll
                    for (int nb = 0; nb < 8; nb++) wv += rec[16+nb]*wr[nb];
                    float hvv = hb[jj];
                    float my = 0.f;
#pragma unroll
                    for (int lm = 0; lm < NLM; lm++) my += M[lm]*rec[lm];
                    Tls[w][jj*68+c] = wv * hvv;
                    Gls[w][jj*68+c] = hvv * my;
                }
                __builtin_amdgcn_wave_barrier();
                {
                    int jj = c >> 4, lm = c & 15;
                    if (jj < ncq) {
                        const float4* mrow = (const float4*)&Mls[w][lm*68];
                        const float4* trow = (const float4*)&Tls[w][jj*68];
                        float s_ = 0.f;
#pragma unroll
                        for (int k4 = 0; k4 < 16; k4++) {
                            float4 mm = mrow[k4]; float4 tv = trow[k4];
                            s_ += mm.x*tv.x + mm.y*tv.y + mm.z*tv.z + mm.w*tv.w;
                        }
                        gols[w][jj*24+lm] = s_ + gYp[(size_t)(base + cb + jj)*16+lm];
                    }
                }
                if (c < 32) {
                    int jj = c >> 3, nb = c & 7;
                    if (jj < ncq) {
                        const float4* wrow = (const float4*)&wrls[nb*68];
                        const float4* grow = (const float4*)&Gls[w][jj*68];
                        float s_ = 0.f;
#pragma unroll
                        for (int k4 = 0; k4 < 16; k4++) {
                            float4 wv4 = wrow[k4]; float4 gv = grow[k4];
                            s_ += wv4.x*gv.x + wv4.y*gv.y + wv4.z*gv.z + wv4.w*gv.w;
                        }
                        gols[w][jj*24+16+nb] = s_ + gRp[(size_t)(base + cb + jj)*8+nb];
                    }
                }
                __builtin_amdgcn_wave_barrier();
                if ((c & 15) == 0) {
                    int jj = c >> 4;
                    if (jj < ncq) {
                        int pp = base + cb + jj;
                        const float* go = &gols[w][jj*24];
                        float4 ul = ((const float4*)UL)[pp];
                        float x = ul.x, y = ul.y, z = ul.z, len = ul.w;
                        float x2 = x*x, y2 = y*y, z2 = z*z;
                        float gx = 0.f, gy = 0.f, gz = 0.f;
                        gx += 0.4886025119029199f*go[3];
                        gy += 0.4886025119029199f*go[1];
                        gz += 0.4886025119029199f*go[2];
                        gx += 1.0925484305920792f*y*go[4];  gy += 1.0925484305920792f*x*go[4];
                        gy += 1.0925484305920792f*z*go[5];  gz += 1.0925484305920792f*y*go[5];
                        gz += 1.8923493915151203f*z*go[6];
                        gx += 1.0925484305920792f*z*go[7];  gz += 1.0925484305920792f*x*go[7];
                        gx += 1.0925484305920792f*x*go[8];  gy -= 1.0925484305920792f*y*go[8];
                        gx += 3.540261539559861f*x*y*go[9];
                        gy += 0.5900435899266435f*(3.f*x2 - 3.f*y2)*go[9];
                        gx += 2.890611442640554f*y*z*go[10]; gy += 2.890611442640554f*x*z*go[10]; gz += 2.890611442640554f*x*y*go[10];
                        gy += 0.4570457994644658f*(5.f*z2 - 1.f)*go[11]; gz += 4.570457994644658f*y*z*go[11];
                        gz += 0.3731763325901154f*(15.f*z2 - 3.f)*go[12];
                        gx += 0.4570457994644658f*(5.f*z2 - 1.f)*go[13]; gz += 4.570457994644658f*x*z*go[13];
                        gx += 2.890611442640554f*x*z*go[14]; gy -= 2.890611442640554f*y*z*go[14];
                        gz += 1.445305721320277f*(x2 - y2)*go[14];
                        gx += 0.5900435899266435f*(3.f*x2 - 3.f*y2)*go[15];
                        gy -= 3.540261539559861f*x*y*go[15];
                        float ur = len * 0.2f;
                        float u2 = ur*ur, u4 = u2*u2, u5 = u4*ur, u6 = u5*ur, u7 = u6*ur;
                        float poly  = 1.f - 21.f*u5 + 35.f*u6 - 15.f*u7;
                        float dpoly = (-105.f*u4 + 210.f*u5 - 105.f*u6)*0.2f;
                        const float s2f = 0.632455532033676f;
                        const float k1 = PI_F/5.f;
                        float th = k1*len;
                        float s1, c1; sincosf(th, &s1, &c1);
                        float sn_ = s1, cs = c1;
                        float inv_r = 1.f/len;
                        bool tiny = (len < 2e-3f);
                        float gL = 0.f;
#pragma unroll
                        for (int nb = 0; nb < 8; nb++) {
                            float kn = k1*(float)(nb+1);
                            float bes = s2f*sn_*inv_r;
                            float dbes;
                            if (tiny) dbes = -s2f*kn*kn*kn*len*(1.f/3.f);
                            else      dbes = s2f*(kn*cs - sn_*inv_r)*inv_r;
                            gL += go[16+nb]*(dbes*poly + bes*dpoly);
                            float ns = sn_*c1 + cs*s1;
                            float nc = cs*c1 - sn_*s1;
                            sn_ = ns; cs = nc;
                        }
                        float dot = gx*x + gy*y + gz*z;
                        float gvx = (gx - dot*x)*inv_r + gL*x;
                        float gvy = (gy - dot*y)*inv_r + gL*y;
                        float gvz = (gz - dot*z)*inv_r + gL*z;
                        int sn2 = sS[w][cb+jj];
                        atomicAdd(&F[n*3+0], -gvx);
                        atomicAdd(&F[n*3+1], -gvy);
                        atomicAdd(&F[n*3+2], -gvz);
                        atomicAdd(&F[sn2*3+0],  gvx);
                        atomicAdd(&F[sn2*3+1],  gvy);
                        atomicAdd(&F[sn2*3+2],  gvz);
                    }
                }
                __builtin_amdgcn_wave_barrier();
            }
        }
    }
}

extern "C" void kernel_launch(void* const* d_in, const int* in_sizes, int n_in,
                              void* d_out, int out_size, void* d_ws, size_t ws_size,
                              hipStream_t stream)
{
    const float* positions  = (const float*)d_in[0];
    const float* node_attrs = (const float*)d_in[1];
    const float* shifts     = (const float*)d_in[2];
    const float* W_embed    = (const float*)d_in[3];
    const float* aew        = (const float*)d_in[4];
    const float* W_rad      = (const float*)d_in[5];
    const float* W_prod     = (const float*)d_in[6];
    const float* w_read     = (const float*)d_in[7];
    const int*   edge_index = (const int*)d_in[8];
    const int*   batch      = (const int*)d_in[9];
    float* out = (float*)d_out;

    const int* snd = edge_index;
    const int* rcv = edge_index + NE;

    char* ws = (char*)d_ws;
    size_t off = 0;
    auto allocf = [&](size_t nelems) -> float* {
        float* p = (float*)(ws + off); off += nelems * sizeof(float); return p;
    };
    float* Y    = allocf((size_t)NE*16);
    float* R    = allocf((size_t)NE*8);
    float* U    = allocf((size_t)NE*3);
    float* L    = allocf((size_t)NE);
    float* PK   = allocf((size_t)NE*24);
    float* UL   = allocf((size_t)NE*4);
    float* H0   = allocf((size_t)NN*CC);
    float* H1   = allocf((size_t)NN*CC);
    float* A0   = allocf((size_t)NN*1024);
    float* GYP  = allocf((size_t)NE*16);
    float* GRP  = allocf((size_t)NE*8);
    float* VB1  = allocf((size_t)NEL*256);
    float* GH1  = allocf((size_t)NN*CC);      // zeroed in k_scatpack
    // --- contiguous zero region: CNT + CUR + ECUR ---
    size_t zero_off = off;
    int* CNT   = (int*)(ws + off); off += (size_t)NN*4;
    int* CUR   = (int*)(ws + off); off += (size_t)NN*4;
    int* ECUR  = (int*)(ws + off); off += 16*4;
    size_t zero_bytes = off - zero_off;
    // --- rest ---
    int* ELEM  = (int*)(ws + off); off += (size_t)NN*4;
    int* OFFS  = (int*)(ws + off); off += (size_t)(NN+1)*4;
    int* SSND  = (int*)(ws + off); off += (size_t)NE*4;
    int* ELOFF = (int*)(ws + off); off += 16*4;
    int* NBE   = (int*)(ws + off); off += (size_t)NN*4;

    hipMemsetAsync(ws + zero_off, 0, zero_bytes, stream);

    const float* Wrad0  = W_rad;
    const float* Wrad1  = W_rad + 8*CC;
    const float* Wprod0 = W_prod;
    const float* Wprod1 = W_prod + (size_t)NEL*256*CC;

    k_front<<<256 + 512 + NEL, 256, 0, stream>>>(
        positions, shifts, snd, rcv, Y, R, U, L, CNT,
        node_attrs, W_embed, H0, ELEM, Wprod1, w_read, VB1);
    k_scan<<<1, 1024, 0, stream>>>(CNT, OFFS, ELEM, ELOFF);
    k_scatpack<<<NE/256, 256, 0, stream>>>(snd, rcv, Y, R, U, L, OFFS, CUR,
                                           PK, SSND, UL, ELEM, ELOFF, ECUR, NBE,
                                           GH1, out);

    k_fwd0<<<NN/16, 256, 0, stream>>>(PK, SSND, Wrad0, Wprod0, H0, node_attrs, ELEM,
                                      OFFS, NBE, H1, A0);
    k_fbwd1<<<NN/16, 256, 0, stream>>>(PK, SSND, Wrad1, H1, VB1, node_attrs, aew, ELEM,
                                       batch, OFFS, GYP, GRP, GH1, out);
    k_fbwd0geo<<<NN/16, 256, 0, stream>>>(PK, SSND, Wrad0, H0, GH1, Wprod0, A0,
                                          node_attrs, ELEM, OFFS, NBE,
                                          GYP, GRP, UL, out + NG);
    (void)in_sizes; (void)n_in; (void)out_size; (void)ws_size;
}